// Round 11
// baseline (180.467 us; speedup 1.0000x reference)
//
#include <hip/hip_runtime.h>
#include <hip/hip_bf16.h>

typedef unsigned short u16;
typedef unsigned int u32;
typedef short s16x8 __attribute__((ext_vector_type(8)));
typedef short s16x4 __attribute__((ext_vector_type(4)));
typedef float f32x4 __attribute__((ext_vector_type(4)));
typedef float f32x16 __attribute__((ext_vector_type(16)));

// fp32 -> bf16 round-to-nearest-even
__device__ inline u16 f2bf(float f) {
  union { float f; unsigned int u; } v; v.f = f;
  unsigned int r = v.u + 0x7fffu + ((v.u >> 16) & 1u);
  return (u16)(r >> 16);
}

// pack two f32 -> bf16x2 in one instruction (no builtin on gfx950)
__device__ __forceinline__ u32 cvt_pk_bf16(float lo, float hi) {
  u32 r;
  asm("v_cvt_pk_bf16_f32 %0, %1, %2" : "=v"(r) : "v"(lo), "v"(hi));
  return r;
}

// async 16B global -> LDS DMA (lane i of the wave lands at ldsbase + i*16)
__device__ __forceinline__ void g2lds16(const u16* g, u16* l) {
  __builtin_amdgcn_global_load_lds((const __attribute__((address_space(1))) void*)g,
                                   (__attribute__((address_space(3))) void*)l, 16, 0, 0);
}

// ---------------------------------------------------------------- fused pre-pass:
// blocks x<40: W transpose+cast (64x64 tiles); x>=40: x cast (id = (x-40)*8+y)
__global__ __launch_bounds__(256) void prep_kernel(const float* __restrict__ x, u16* __restrict__ xb,
                                                   const float* __restrict__ Wq,
                                                   const float* __restrict__ Wk,
                                                   const float* __restrict__ Wv,
                                                   u16* __restrict__ wt) {
  if (blockIdx.x >= 40) {
    int i = (((blockIdx.x - 40) * 8 + blockIdx.y) * 256 + threadIdx.x) * 8;
    float4 a = *(const float4*)(x + i);
    float4 b = *(const float4*)(x + i + 4);
    s16x8 o;
    o[0] = (short)f2bf(a.x); o[1] = (short)f2bf(a.y);
    o[2] = (short)f2bf(a.z); o[3] = (short)f2bf(a.w);
    o[4] = (short)f2bf(b.x); o[5] = (short)f2bf(b.y);
    o[6] = (short)f2bf(b.z); o[7] = (short)f2bf(b.w);
    *(s16x8*)(xb + i) = o;
    return;
  }
  __shared__ float tile[64][65];
  int jg = blockIdx.x * 64;
  const float* src; int C, j0;
  if (jg < 1024)      { src = Wq; C = 1024; j0 = jg; }
  else if (jg < 2048) { src = Wk; C = 1024; j0 = jg - 1024; }
  else                { src = Wv; C = 512;  j0 = jg - 2048; }
  int k0 = blockIdx.y * 64;
  int tx = threadIdx.x % 64, ty4 = threadIdx.x / 64;
#pragma unroll
  for (int p = 0; p < 16; ++p) {
    int r = p * 4 + ty4;
    tile[r][tx] = src[(size_t)(k0 + r) * C + j0 + tx];
  }
  __syncthreads();
#pragma unroll
  for (int p = 0; p < 16; ++p) {
    int r = p * 4 + ty4;
    wt[(size_t)(jg + r) * 512 + k0 + tx] = f2bf(tile[tx][r]);
  }
}

// ---------------------------------------------------------------- fused QKV projection GEMM
// (m97 recipe). V-blocks (j0>=2048): operand-swapped MFMAs -> C^T -> coalesced va stores
// (verified R10). Q outputs are PRE-SCALED by 0.18033688 (=1/sqrt(64)/ln2) so attn's
// exp2 input needs no per-element multiply.
__global__ __launch_bounds__(256, 2) void gemm_qkv(const u16* __restrict__ xb, const u16* __restrict__ wt,
                                                   const float* __restrict__ bq, const float* __restrict__ bk,
                                                   const float* __restrict__ bv,
                                                   u16* __restrict__ qa, u16* __restrict__ ka,
                                                   u16* __restrict__ va) {
  __shared__ __align__(16) u16 As[128 * 64];
  __shared__ __align__(16) u16 Bs[128 * 64];
  int m0 = blockIdx.x * 128, j0 = blockIdx.y * 128;
  bool isV = (j0 >= 2048);
  int tid = threadIdx.x;
  int w = tid >> 6, lane = tid & 63, quad = lane >> 4, l16 = lane & 15;
  int wr = (w >> 1) * 64, wc = (w & 1) * 64;

  int srow[4], scol[4], sbase[4];
#pragma unroll
  for (int it = 0; it < 4; ++it) {
    int s = it * 256 + tid;
    srow[it] = s >> 3;
    scol[it] = (s & 7) ^ ((s >> 3) & 7);
    sbase[it] = (s & ~63) * 8;
  }

  f32x4 acc[4][4];
#pragma unroll
  for (int i = 0; i < 4; ++i)
#pragma unroll
    for (int j = 0; j < 4; ++j)
#pragma unroll
      for (int r = 0; r < 4; ++r) acc[i][j][r] = 0.f;

  for (int kk = 0; kk < 8; ++kk) {
    int k0 = kk * 64;
    __syncthreads();
#pragma unroll
    for (int it = 0; it < 4; ++it) {
      g2lds16(xb + (size_t)(m0 + srow[it]) * 512 + k0 + scol[it] * 8, &As[sbase[it]]);
      g2lds16(wt + (size_t)(j0 + srow[it]) * 512 + k0 + scol[it] * 8, &Bs[sbase[it]]);
    }
    __syncthreads();
#pragma unroll
    for (int kb = 0; kb < 2; ++kb) {
      s16x8 af[4], bfr[4];
#pragma unroll
      for (int rb = 0; rb < 4; ++rb) {
        int row = wr + rb * 16 + l16;
        af[rb] = *(const s16x8*)(&As[row * 64 + (((kb * 4 + quad) ^ (row & 7)) * 8)]);
      }
#pragma unroll
      for (int cb = 0; cb < 4; ++cb) {
        int row = wc + cb * 16 + l16;
        bfr[cb] = *(const s16x8*)(&Bs[row * 64 + (((kb * 4 + quad) ^ (row & 7)) * 8)]);
      }
      if (isV) {
#pragma unroll
        for (int rb = 0; rb < 4; ++rb)
#pragma unroll
          for (int cb = 0; cb < 4; ++cb)
            acc[rb][cb] = __builtin_amdgcn_mfma_f32_16x16x32_bf16(bfr[cb], af[rb], acc[rb][cb], 0, 0, 0);
      } else {
#pragma unroll
        for (int rb = 0; rb < 4; ++rb)
#pragma unroll
          for (int cb = 0; cb < 4; ++cb)
            acc[rb][cb] = __builtin_amdgcn_mfma_f32_16x16x32_bf16(af[rb], bfr[cb], acc[rb][cb], 0, 0, 0);
      }
    }
  }

  if (isV) {
    // transposed acc: row(quad*4+r) -> j, col(l16) -> m. Lanes -> consecutive n.
#pragma unroll
    for (int cb = 0; cb < 4; ++cb) {
#pragma unroll
      for (int rb = 0; rb < 4; ++rb) {
        int m = m0 + wr + rb * 16 + l16;
        int bidx = m >> 10, n = m & 1023;
#pragma unroll
        for (int r = 0; r < 4; ++r) {
          int jj = j0 - 2048 + wc + cb * 16 + quad * 4 + r;
          int h = jj >> 6, d = jj & 63;
          float bias = bv[jj];
          va[((size_t)((bidx * 8 + h) * 64 + d)) * 1024 + n] = f2bf(acc[rb][cb][r] + bias);
        }
      }
    }
  } else {
#pragma unroll
    for (int cb = 0; cb < 4; ++cb) {
      int j = j0 + wc + cb * 16 + l16;
      bool isQ = (j < 1024);
      float bias = isQ ? bq[j] : bk[j - 1024];
#pragma unroll
      for (int rb = 0; rb < 4; ++rb) {
#pragma unroll
        for (int r = 0; r < 4; ++r) {
          int m = m0 + wr + rb * 16 + quad * 4 + r;
          int bidx = m >> 10, n = m & 1023;
          float val = acc[rb][cb][r] + bias;
          u16 o = f2bf(isQ ? val * 0.18033688f : val);   // pre-scale Q for attn's exp2
          if (isQ) {
            int h = j >> 7, r2 = j & 127;
            qa[((size_t)((bidx * 8 + h) * 1024 + n)) * 128 + r2] = o;
          } else {
            int jj = j - 1024, h = jj >> 7, r2 = jj & 127;
            ka[((size_t)((bidx * 8 + h) * 1024 + n)) * 128 + r2] = o;
          }
        }
      }
    }
  }
}

// ---------------------------------------------------------------- differential attention v10
// v8 structure (best measured) with source-level VALU strength reduction:
//  - staging via 8 K-ptrs + 4 V-ptrs advanced by constant stride per tile (no 64-bit
//    mul/addressing recompute), DMA dests precomputed;
//  - ALL LDS read offsets precomputed once (compile-time-indexed arrays stay in regs);
//  - kt loop unrolled x2 so the K double-buffer base is a compile-time constant;
//  - Q pre-scaled in gemm -> exp2 input is the raw MFMA output (no per-element mul);
//  - V fragments loaded before QK MFMAs; pairwise denominator reduction.
// Geometry unchanged: 2 teams x 2 waves, 80KB LDS, 2 blocks/CU.
__global__ __launch_bounds__(256, 2) void attn_kernel(const u16* __restrict__ qa, const u16* __restrict__ ka,
                                                      const u16* __restrict__ va, float* __restrict__ out) {
  __shared__ __align__(16) u16 smem[40960];   // 81920 B: two 40KB team halves
  int bh = blockIdx.x, b = bh >> 3, h = bh & 7;
  int q0 = blockIdx.y * 64;
  int tid = threadIdx.x, w = tid >> 6, lane = tid & 63;
  int l32 = lane & 31, hi = lane >> 5;
  int team = w >> 1, wq = w & 1, t = tid & 127;
  u16* hb = smem + team * 20480;
  u16* const KbA = hb;            // 8192 u16 (64n x 128k), XOR-swizzled chunks
  u16* const KbB = hb + 8192;
  u16* const Vsb = hb + 16384;    // 4096 u16 (64d x 64n), XOR-swizzled chunks

  // Q fragments (pre-scaled): B-side of swapped QK. col=q=l32
  const u16* qrow = qa + (size_t)(bh * 1024 + q0 + wq * 32 + l32) * 128;
  s16x8 qf[2][4];
#pragma unroll
  for (int hh = 0; hh < 2; ++hh)
#pragma unroll
    for (int kb = 0; kb < 4; ++kb)
      qf[hh][kb] = *(const s16x8*)(qrow + 64 * hh + 16 * kb + 8 * hi);

  f32x16 O1[2], O2[2];
#pragma unroll
  for (int d = 0; d < 2; ++d)
#pragma unroll
    for (int r = 0; r < 16; ++r) { O1[d][r] = 0.f; O2[d][r] = 0.f; }
  float ds1 = 0.f, ds2 = 0.f;

  // ---- precomputed LDS read offsets (u16 units, rel. to KbA / Vsb)
  int ko[2][2][4];   // [nb][hh][kb]
#pragma unroll
  for (int nb = 0; nb < 2; ++nb) {
    int row = nb * 32 + l32, rb = row * 128, rx = row & 15;
#pragma unroll
    for (int hh = 0; hh < 2; ++hh)
#pragma unroll
      for (int kb = 0; kb < 4; ++kb)
        ko[nb][hh][kb] = rb + (((8 * hh + 2 * kb + hi) ^ rx) * 8);
  }
  int vo[2][4][2];   // [dblk][s][half]
#pragma unroll
  for (int dblk = 0; dblk < 2; ++dblk) {
    int row = dblk * 32 + l32, rb = row * 64, rx = row & 7;
#pragma unroll
    for (int s = 0; s < 4; ++s)
#pragma unroll
      for (int half = 0; half < 2; ++half)
        vo[dblk][s][half] = rb + (((2 * s + half) ^ rx) * 8) + 4 * hi;
  }

  // ---- staging: strength-reduced pointers (per-thread), fixed stride per tile
  int nbase = team * 512;
  const u16* kgbase = ka + (size_t)bh * 1024 * 128;
  const u16* vgbase = va + (size_t)bh * 64 * 1024;
  int r0 = t >> 4, c0 = t & 15;
  int ce = c0 ^ r0, co = c0 ^ (r0 + 8);
  const u16* kp[8];
#pragma unroll
  for (int i2 = 0; i2 < 4; ++i2) {
    kp[2 * i2]     = kgbase + (size_t)(nbase + r0 + 16 * i2) * 128 + ce * 8;
    kp[2 * i2 + 1] = kgbase + (size_t)(nbase + r0 + 16 * i2 + 8) * 128 + co * 8;
  }
  int rv = t >> 3, cv = (t & 7) ^ ((t >> 3) & 7);
  const u16* vp[4];
#pragma unroll
  for (int it = 0; it < 4; ++it)
    vp[it] = vgbase + (size_t)(rv + 16 * it) * 1024 + nbase + cv * 8;
  int dk[8];
#pragma unroll
  for (int it = 0; it < 8; ++it) dk[it] = (it * 128 + (t & 64)) * 8;

  // stage tile 0
#pragma unroll
  for (int it = 0; it < 8; ++it) g2lds16(kp[it], KbA + dk[it]);
#pragma unroll
  for (int it = 0; it < 4; ++it) g2lds16(vp[it], Vsb + dk[it]);
  __syncthreads();   // drain DMA for tile 0

  s16x8 pa[2][4];    // [hh][s]
  s16x8 vB[4][2];    // [s][dblk]

  // one tile body; cur/nxt are compile-time KbA/KbB per copy
  auto body = [&](u16* const cur, u16* const nxt, bool pfK, bool pfV) {
    if (pfK) {   // prefetch K(t+1): advance pointers (fixed stride), issue DMA
#pragma unroll
      for (int it = 0; it < 8; ++it) kp[it] += 64 * 128;
#pragma unroll
      for (int it = 0; it < 8; ++it) g2lds16(kp[it], nxt + dk[it]);
    }
    // V fragments of tile t (LDS pipe busy while QK MFMAs run below)
#pragma unroll
    for (int dblk = 0; dblk < 2; ++dblk)
#pragma unroll
      for (int s = 0; s < 4; ++s) {
        union { s16x4 hl[2]; s16x8 v; } u;
        u.hl[0] = *(const s16x4*)(Vsb + vo[dblk][s][0]);
        u.hl[1] = *(const s16x4*)(Vsb + vo[dblk][s][1]);
        vB[s][dblk] = u.v;
      }
    // QK^T (swapped) + exp2 + in-register pack, per half
#pragma unroll
    for (int hh = 0; hh < 2; ++hh) {
      f32x16 sv[2];
#pragma unroll
      for (int nb = 0; nb < 2; ++nb)
#pragma unroll
        for (int r = 0; r < 16; ++r) sv[nb][r] = 0.f;
#pragma unroll
      for (int nb = 0; nb < 2; ++nb)
#pragma unroll
        for (int kb = 0; kb < 4; ++kb) {
          s16x8 kf = *(const s16x8*)(cur + ko[nb][hh][kb]);
          sv[nb] = __builtin_amdgcn_mfma_f32_32x32x16_bf16(kf, qf[hh][kb], sv[nb], 0, 0, 0);
        }
      float dsl = 0.f;
#pragma unroll
      for (int s = 0; s < 4; ++s) {
        float e[8];
#pragma unroll
        for (int j = 0; j < 8; ++j)
          e[j] = __builtin_exp2f(sv[s >> 1][(s & 1) * 8 + j]);
        dsl += ((e[0] + e[1]) + (e[2] + e[3])) + ((e[4] + e[5]) + (e[6] + e[7]));
        union { u32 wd[4]; s16x8 v; } u;
        u.wd[0] = cvt_pk_bf16(e[0], e[1]);
        u.wd[1] = cvt_pk_bf16(e[2], e[3]);
        u.wd[2] = cvt_pk_bf16(e[4], e[5]);
        u.wd[3] = cvt_pk_bf16(e[6], e[7]);
        pa[hh][s] = u.v;
      }
      if (hh == 0) ds1 += dsl; else ds2 += dsl;
    }
    // Barrier A: all LDS reads landed in regs -> Vsb may be overwritten.
    // lgkm-only: the K prefetch DMA keeps flying.
    asm volatile("s_waitcnt lgkmcnt(0)\n\ts_barrier" ::: "memory");
    if (pfV) {   // stage V(t+1); cover = PV below
#pragma unroll
      for (int it = 0; it < 4; ++it) vp[it] += 64;
#pragma unroll
      for (int it = 0; it < 4; ++it) g2lds16(vp[it], Vsb + dk[it]);
    }
    // PV: O[q][d] += P[q][n] V[n][d]
#pragma unroll
    for (int s = 0; s < 4; ++s)
#pragma unroll
      for (int dblk = 0; dblk < 2; ++dblk) {
        O1[dblk] = __builtin_amdgcn_mfma_f32_32x32x16_bf16(pa[0][s], vB[s][dblk], O1[dblk], 0, 0, 0);
        O2[dblk] = __builtin_amdgcn_mfma_f32_32x32x16_bf16(pa[1][s], vB[s][dblk], O2[dblk], 0, 0, 0);
      }
    __syncthreads();   // Barrier B: drains K+V prefetch DMA
  };

  for (int kt2 = 0; kt2 < 4; ++kt2) {
    body(KbA, KbB, true, true);                    // tiles 0,2,4,6: always prefetch
    body(KbB, KbA, kt2 < 3, kt2 < 3);              // tiles 1,3,5,7: last has none
  }

  // ---- epilogue: merge team partials via LDS scratch, normalize, combine, store
  float* scr = (float*)smem;   // 33.8KB over freed buffers
  int mbase = wq * 4224 + lane;
  if (team == 1) {
#pragma unroll
    for (int r = 0; r < 16; ++r) {
      scr[mbase + r * 64]        = O1[0][r];
      scr[mbase + (16 + r) * 64] = O1[1][r];
      scr[mbase + (32 + r) * 64] = O2[0][r];
      scr[mbase + (48 + r) * 64] = O2[1][r];
    }
    scr[mbase + 64 * 64] = ds1;
    scr[mbase + 65 * 64] = ds2;
  }
  __syncthreads();
  if (team == 0) {
#pragma unroll
    for (int r = 0; r < 16; ++r) {
      O1[0][r] += scr[mbase + r * 64];
      O1[1][r] += scr[mbase + (16 + r) * 64];
      O2[0][r] += scr[mbase + (32 + r) * 64];
      O2[1][r] += scr[mbase + (48 + r) * 64];
    }
    ds1 += scr[mbase + 64 * 64];
    ds2 += scr[mbase + 65 * 64];
    ds1 += __shfl_xor(ds1, 32, 64);   // combine the two hi-halves' n-subsets
    ds2 += __shfl_xor(ds2, 32, 64);
    float inv1 = 1.0f / ds1, inv2 = 1.0f / ds2;   // lane l holds inv for q = l32
#pragma unroll
    for (int r = 0; r < 16; ++r) {
      int iq = (r & 3) + 8 * (r >> 2) + 4 * hi;   // this reg's q within the wave's 32
      float i1 = __shfl(inv1, iq, 64);
      float i2 = __shfl(inv2, iq, 64);
      size_t orow = (size_t)(b * 1024 + q0 + wq * 32 + iq) * 512 + h * 64 + l32;
      out[orow]      = O1[0][r] * i1 - 0.5f * O2[0][r] * i2;
      out[orow + 32] = O1[1][r] * i1 - 0.5f * O2[1][r] * i2;
    }
  }
}

// ---------------------------------------------------------------- launcher
extern "C" void kernel_launch(void* const* d_in, const int* in_sizes, int n_in,
                              void* d_out, int out_size, void* d_ws, size_t ws_size,
                              hipStream_t stream) {
  (void)in_sizes; (void)n_in; (void)out_size; (void)ws_size;
  const float* x  = (const float*)d_in[0];
  const float* Wq = (const float*)d_in[1];
  const float* bq = (const float*)d_in[2];
  const float* Wk = (const float*)d_in[3];
  const float* bk = (const float*)d_in[4];
  const float* Wv = (const float*)d_in[5];
  const float* bv = (const float*)d_in[6];
  float* out = (float*)d_out;

  char* ws = (char*)d_ws;
  u16* xb = (u16*)(ws);                    // 4096*512*2   = 4 MiB
  u16* wt = (u16*)(ws + 4194304);          // 2560*512*2   = 2.5 MiB
  u16* qa = (u16*)(ws + 6815744);          // 4*8*1024*128*2 = 8 MiB
  u16* ka = (u16*)(ws + 15204352);         // 8 MiB
  u16* va = (u16*)(ws + 23592960);         // 4*8*64*1024*2 = 4 MiB

  prep_kernel<<<dim3(168, 8), 256, 0, stream>>>(x, xb, Wq, Wk, Wv, wt);
  gemm_qkv<<<dim3(32, 20), 256, 0, stream>>>(xb, wt, bq, bk, bv, qa, ka, va);
  attn_kernel<<<dim3(32, 16), 256, 0, stream>>>(qa, ka, va, out);
}

// Round 12
// 132.880 us; speedup vs baseline: 1.3581x; 1.3581x over previous
//
#include <hip/hip_runtime.h>
#include <hip/hip_bf16.h>

typedef unsigned short u16;
typedef unsigned int u32;
typedef short s16x8 __attribute__((ext_vector_type(8)));
typedef short s16x4 __attribute__((ext_vector_type(4)));
typedef float f32x4 __attribute__((ext_vector_type(4)));
typedef float f32x16 __attribute__((ext_vector_type(16)));

// fp32 -> bf16 round-to-nearest-even
__device__ inline u16 f2bf(float f) {
  union { float f; unsigned int u; } v; v.f = f;
  unsigned int r = v.u + 0x7fffu + ((v.u >> 16) & 1u);
  return (u16)(r >> 16);
}

// pack two f32 -> bf16x2 in one instruction (no builtin on gfx950)
__device__ __forceinline__ u32 cvt_pk_bf16(float lo, float hi) {
  u32 r;
  asm("v_cvt_pk_bf16_f32 %0, %1, %2" : "=v"(r) : "v"(lo), "v"(hi));
  return r;
}

// async 16B global -> LDS DMA (lane i of the wave lands at ldsbase + i*16)
__device__ __forceinline__ void g2lds16(const u16* g, u16* l) {
  __builtin_amdgcn_global_load_lds((const __attribute__((address_space(1))) void*)g,
                                   (__attribute__((address_space(3))) void*)l, 16, 0, 0);
}

// ---------------------------------------------------------------- fused pre-pass:
// blocks x<40: W transpose+cast (64x64 tiles); x>=40: x cast (id = (x-40)*8+y)
__global__ __launch_bounds__(256) void prep_kernel(const float* __restrict__ x, u16* __restrict__ xb,
                                                   const float* __restrict__ Wq,
                                                   const float* __restrict__ Wk,
                                                   const float* __restrict__ Wv,
                                                   u16* __restrict__ wt) {
  if (blockIdx.x >= 40) {
    int i = (((blockIdx.x - 40) * 8 + blockIdx.y) * 256 + threadIdx.x) * 8;
    float4 a = *(const float4*)(x + i);
    float4 b = *(const float4*)(x + i + 4);
    s16x8 o;
    o[0] = (short)f2bf(a.x); o[1] = (short)f2bf(a.y);
    o[2] = (short)f2bf(a.z); o[3] = (short)f2bf(a.w);
    o[4] = (short)f2bf(b.x); o[5] = (short)f2bf(b.y);
    o[6] = (short)f2bf(b.z); o[7] = (short)f2bf(b.w);
    *(s16x8*)(xb + i) = o;
    return;
  }
  __shared__ float tile[64][65];
  int jg = blockIdx.x * 64;
  const float* src; int C, j0;
  if (jg < 1024)      { src = Wq; C = 1024; j0 = jg; }
  else if (jg < 2048) { src = Wk; C = 1024; j0 = jg - 1024; }
  else                { src = Wv; C = 512;  j0 = jg - 2048; }
  int k0 = blockIdx.y * 64;
  int tx = threadIdx.x % 64, ty4 = threadIdx.x / 64;
#pragma unroll
  for (int p = 0; p < 16; ++p) {
    int r = p * 4 + ty4;
    tile[r][tx] = src[(size_t)(k0 + r) * C + j0 + tx];
  }
  __syncthreads();
#pragma unroll
  for (int p = 0; p < 16; ++p) {
    int r = p * 4 + ty4;
    wt[(size_t)(jg + r) * 512 + k0 + tx] = f2bf(tile[tx][r]);
  }
}

// ---------------------------------------------------------------- fused QKV projection GEMM
// (m97 recipe). V-blocks (j0>=2048): operand-swapped MFMAs -> C^T -> coalesced va stores
// (verified R10). Q outputs PRE-SCALED by 0.18033688 (=1/sqrt(64)*log2(e)) so attn's
// exp2 input needs no per-element multiply (validated numerically in R11's passing run).
__global__ __launch_bounds__(256, 2) void gemm_qkv(const u16* __restrict__ xb, const u16* __restrict__ wt,
                                                   const float* __restrict__ bq, const float* __restrict__ bk,
                                                   const float* __restrict__ bv,
                                                   u16* __restrict__ qa, u16* __restrict__ ka,
                                                   u16* __restrict__ va) {
  __shared__ __align__(16) u16 As[128 * 64];
  __shared__ __align__(16) u16 Bs[128 * 64];
  int m0 = blockIdx.x * 128, j0 = blockIdx.y * 128;
  bool isV = (j0 >= 2048);
  int tid = threadIdx.x;
  int w = tid >> 6, lane = tid & 63, quad = lane >> 4, l16 = lane & 15;
  int wr = (w >> 1) * 64, wc = (w & 1) * 64;

  int srow[4], scol[4], sbase[4];
#pragma unroll
  for (int it = 0; it < 4; ++it) {
    int s = it * 256 + tid;
    srow[it] = s >> 3;
    scol[it] = (s & 7) ^ ((s >> 3) & 7);
    sbase[it] = (s & ~63) * 8;
  }

  f32x4 acc[4][4];
#pragma unroll
  for (int i = 0; i < 4; ++i)
#pragma unroll
    for (int j = 0; j < 4; ++j)
#pragma unroll
      for (int r = 0; r < 4; ++r) acc[i][j][r] = 0.f;

  for (int kk = 0; kk < 8; ++kk) {
    int k0 = kk * 64;
    __syncthreads();
#pragma unroll
    for (int it = 0; it < 4; ++it) {
      g2lds16(xb + (size_t)(m0 + srow[it]) * 512 + k0 + scol[it] * 8, &As[sbase[it]]);
      g2lds16(wt + (size_t)(j0 + srow[it]) * 512 + k0 + scol[it] * 8, &Bs[sbase[it]]);
    }
    __syncthreads();
#pragma unroll
    for (int kb = 0; kb < 2; ++kb) {
      s16x8 af[4], bfr[4];
#pragma unroll
      for (int rb = 0; rb < 4; ++rb) {
        int row = wr + rb * 16 + l16;
        af[rb] = *(const s16x8*)(&As[row * 64 + (((kb * 4 + quad) ^ (row & 7)) * 8)]);
      }
#pragma unroll
      for (int cb = 0; cb < 4; ++cb) {
        int row = wc + cb * 16 + l16;
        bfr[cb] = *(const s16x8*)(&Bs[row * 64 + (((kb * 4 + quad) ^ (row & 7)) * 8)]);
      }
      if (isV) {
#pragma unroll
        for (int rb = 0; rb < 4; ++rb)
#pragma unroll
          for (int cb = 0; cb < 4; ++cb)
            acc[rb][cb] = __builtin_amdgcn_mfma_f32_16x16x32_bf16(bfr[cb], af[rb], acc[rb][cb], 0, 0, 0);
      } else {
#pragma unroll
        for (int rb = 0; rb < 4; ++rb)
#pragma unroll
          for (int cb = 0; cb < 4; ++cb)
            acc[rb][cb] = __builtin_amdgcn_mfma_f32_16x16x32_bf16(af[rb], bfr[cb], acc[rb][cb], 0, 0, 0);
      }
    }
  }

  if (isV) {
    // transposed acc: row(quad*4+r) -> j, col(l16) -> m. Lanes -> consecutive n.
#pragma unroll
    for (int cb = 0; cb < 4; ++cb) {
#pragma unroll
      for (int rb = 0; rb < 4; ++rb) {
        int m = m0 + wr + rb * 16 + l16;
        int bidx = m >> 10, n = m & 1023;
#pragma unroll
        for (int r = 0; r < 4; ++r) {
          int jj = j0 - 2048 + wc + cb * 16 + quad * 4 + r;
          int h = jj >> 6, d = jj & 63;
          float bias = bv[jj];
          va[((size_t)((bidx * 8 + h) * 64 + d)) * 1024 + n] = f2bf(acc[rb][cb][r] + bias);
        }
      }
    }
  } else {
#pragma unroll
    for (int cb = 0; cb < 4; ++cb) {
      int j = j0 + wc + cb * 16 + l16;
      bool isQ = (j < 1024);
      float bias = isQ ? bq[j] : bk[j - 1024];
#pragma unroll
      for (int rb = 0; rb < 4; ++rb) {
#pragma unroll
        for (int r = 0; r < 4; ++r) {
          int m = m0 + wr + rb * 16 + quad * 4 + r;
          int bidx = m >> 10, n = m & 1023;
          float val = acc[rb][cb][r] + bias;
          u16 o = f2bf(isQ ? val * 0.18033688f : val);   // pre-scale Q for attn's exp2
          if (isQ) {
            int h = j >> 7, r2 = j & 127;
            qa[((size_t)((bidx * 8 + h) * 1024 + n)) * 128 + r2] = o;
          } else {
            int jj = j - 1024, h = jj >> 7, r2 = jj & 127;
            ka[((size_t)((bidx * 8 + h) * 1024 + n)) * 128 + r2] = o;
          }
        }
      }
    }
  }
}

// ---------------------------------------------------------------- differential attention v8 (best measured; R10 verbatim
// except exp2 takes the pre-scaled QK output directly — no per-element multiply).
// In-block K-split, 32x32 MFMAs, register-resident P via the verified k(n)-permutation,
// VALU denominator, LDS-staged K (dbuf) + V (single + lgkm-only barrier A).
// 80KB/block, 2 blocks/CU, 2 waves/SIMD.
__global__ __launch_bounds__(256, 2) void attn_kernel(const u16* __restrict__ qa, const u16* __restrict__ ka,
                                                      const u16* __restrict__ va, float* __restrict__ out) {
  __shared__ __align__(16) u16 smem[40960];   // 81920 B: two 40KB team halves
  int bh = blockIdx.x, b = bh >> 3, h = bh & 7;
  int q0 = blockIdx.y * 64;
  int tid = threadIdx.x, w = tid >> 6, lane = tid & 63;
  int l32 = lane & 31, hi = lane >> 5;
  int team = w >> 1, wq = w & 1, t = tid & 127;
  u16* hb = smem + team * 20480;
  u16* const KbA = hb;            // 8192 u16 (64n x 128k)
  u16* const KbB = hb + 8192;
  u16* const Vsb = hb + 16384;    // 4096 u16 (64d x 64n)

  // Q fragments (pre-scaled): B-side of swapped QK. col=q=l32; k-els at 64*hh + 16*kb + 8*hi + j
  const u16* qrow = qa + (size_t)(bh * 1024 + q0 + wq * 32 + l32) * 128;
  s16x8 qf[2][4];
#pragma unroll
  for (int hh = 0; hh < 2; ++hh)
#pragma unroll
    for (int kb = 0; kb < 4; ++kb)
      qf[hh][kb] = *(const s16x8*)(qrow + 64 * hh + 16 * kb + 8 * hi);

  f32x16 O1[2], O2[2];
#pragma unroll
  for (int d = 0; d < 2; ++d)
#pragma unroll
    for (int r = 0; r < 16; ++r) { O1[d][r] = 0.f; O2[d][r] = 0.f; }
  float ds1 = 0.f, ds2 = 0.f;

  // staging precompute (per 128-thread team)
  int r0 = t >> 4, c0 = t & 15;              // K: row base (8 rows/iter), 16 chunks/row
  int rv = t >> 3, cv = (t & 7) ^ ((t >> 3) & 7);  // V: chunk constant across iters
  const u16* kgbase = ka + (size_t)bh * 1024 * 128;
  const u16* vgbase = va + (size_t)bh * 64 * 1024;
  int nbase = team * 512;                    // this team's n range

  auto stageK = [&](int n0, u16* Kd) {
#pragma unroll
    for (int it = 0; it < 8; ++it) {
      int row = r0 + 8 * it;
      int chunk = c0 ^ (row & 15);           // inverse-swizzled source (rule 21)
      g2lds16(kgbase + (size_t)(n0 + row) * 128 + chunk * 8, Kd + (it * 128 + (t & 64)) * 8);
    }
  };
  auto stageV = [&](int n0) {
#pragma unroll
    for (int it = 0; it < 4; ++it)
      g2lds16(vgbase + (size_t)(rv + 16 * it) * 1024 + n0 + cv * 8, Vsb + (it * 128 + (t & 64)) * 8);
  };

  stageK(nbase, KbA);
  stageV(nbase);
  __syncthreads();   // drain DMA for tile 0

  for (int kt = 0; kt < 8; ++kt) {
    u16* const KsC = (kt & 1) ? KbB : KbA;
    u16* const KsN = (kt & 1) ? KbA : KbB;
    if (kt < 7) stageK(nbase + (kt + 1) * 64, KsN);  // in flight until barrier B

    // QK^T (swapped) + exp2 + in-register pack, per half
    s16x8 pa[2][4];   // [hh][s]: A-frag for PV step s (n-block 16s..16s+15)
#pragma unroll
    for (int hh = 0; hh < 2; ++hh) {
      f32x16 sv[2];
#pragma unroll
      for (int nb = 0; nb < 2; ++nb)
#pragma unroll
        for (int r = 0; r < 16; ++r) sv[nb][r] = 0.f;
#pragma unroll
      for (int nb = 0; nb < 2; ++nb) {
        int row = nb * 32 + l32, rbase = row * 128, rx15 = row & 15;
#pragma unroll
        for (int kb = 0; kb < 4; ++kb) {
          s16x8 kf = *(const s16x8*)(&KsC[rbase + (((8 * hh + 2 * kb + hi) ^ rx15) * 8)]);
          sv[nb] = __builtin_amdgcn_mfma_f32_32x32x16_bf16(kf, qf[hh][kb], sv[nb], 0, 0, 0);
        }
      }
      float dsl = 0.f;
#pragma unroll
      for (int s = 0; s < 4; ++s) {
        float e[8];
#pragma unroll
        for (int j = 0; j < 8; ++j) {
          e[j] = __builtin_exp2f(sv[s >> 1][(s & 1) * 8 + j]);   // Q pre-scaled in gemm
          dsl += e[j];
        }
        union { u32 wd[4]; s16x8 v; } u;
        u.wd[0] = cvt_pk_bf16(e[0], e[1]);
        u.wd[1] = cvt_pk_bf16(e[2], e[3]);
        u.wd[2] = cvt_pk_bf16(e[4], e[5]);
        u.wd[3] = cvt_pk_bf16(e[6], e[7]);
        pa[hh][s] = u.v;
      }
      if (hh == 0) ds1 += dsl; else ds2 += dsl;
    }

    // V B-frags under the same k(n)-map: lane (d=l32+32dblk, hi) el j holds
    // V[n = 16s + 8*(j>>2) + 4hi + (j&3)][d]  -> two 8B reads from swizzled V^T
    s16x8 vB[4][2];   // [s][dblk]
#pragma unroll
    for (int dblk = 0; dblk < 2; ++dblk) {
      int row = dblk * 32 + l32, rbase = row * 64, rx = row & 7;
#pragma unroll
      for (int s = 0; s < 4; ++s) {
        union { s16x4 hl[2]; s16x8 v; } u;
        u.hl[0] = *(const s16x4*)(&Vsb[rbase + (((2 * s) ^ rx) * 8) + 4 * hi]);
        u.hl[1] = *(const s16x4*)(&Vsb[rbase + (((2 * s + 1) ^ rx) * 8) + 4 * hi]);
        vB[s][dblk] = u.v;
      }
    }

    // Barrier A: all waves' LDS reads (K and V) landed in registers -> Vsb may be overwritten.
    // Deliberately NO vmcnt drain: the K prefetch DMA continues flying.
    asm volatile("s_waitcnt lgkmcnt(0)\n\ts_barrier" ::: "memory");
    if (kt < 7) stageV(nbase + (kt + 1) * 64);   // cover = exp + PV below

    // PV: O[q][d] += P[q][n] V[n][d]; C row -> q, col = d
#pragma unroll
    for (int s = 0; s < 4; ++s)
#pragma unroll
      for (int dblk = 0; dblk < 2; ++dblk) {
        O1[dblk] = __builtin_amdgcn_mfma_f32_32x32x16_bf16(pa[0][s], vB[s][dblk], O1[dblk], 0, 0, 0);
        O2[dblk] = __builtin_amdgcn_mfma_f32_32x32x16_bf16(pa[1][s], vB[s][dblk], O2[dblk], 0, 0, 0);
      }

    __syncthreads();   // Barrier B: drains K+V prefetch DMA (cover = exp + PV)
  }

  // ---- epilogue: merge team partials via LDS scratch, normalize, combine, store
  float* scr = (float*)smem;   // 33.8KB over freed buffers
  int mbase = wq * 4224 + lane;
  if (team == 1) {
#pragma unroll
    for (int r = 0; r < 16; ++r) {
      scr[mbase + r * 64]        = O1[0][r];
      scr[mbase + (16 + r) * 64] = O1[1][r];
      scr[mbase + (32 + r) * 64] = O2[0][r];
      scr[mbase + (48 + r) * 64] = O2[1][r];
    }
    scr[mbase + 64 * 64] = ds1;
    scr[mbase + 65 * 64] = ds2;
  }
  __syncthreads();
  if (team == 0) {
#pragma unroll
    for (int r = 0; r < 16; ++r) {
      O1[0][r] += scr[mbase + r * 64];
      O1[1][r] += scr[mbase + (16 + r) * 64];
      O2[0][r] += scr[mbase + (32 + r) * 64];
      O2[1][r] += scr[mbase + (48 + r) * 64];
    }
    ds1 += scr[mbase + 64 * 64];
    ds2 += scr[mbase + 65 * 64];
    ds1 += __shfl_xor(ds1, 32, 64);   // combine the two hi-halves' n-subsets
    ds2 += __shfl_xor(ds2, 32, 64);
    float inv1 = 1.0f / ds1, inv2 = 1.0f / ds2;   // lane l holds inv for q = l32
#pragma unroll
    for (int r = 0; r < 16; ++r) {
      int iq = (r & 3) + 8 * (r >> 2) + 4 * hi;   // this reg's q within the wave's 32
      float i1 = __shfl(inv1, iq, 64);
      float i2 = __shfl(inv2, iq, 64);
      size_t orow = (size_t)(b * 1024 + q0 + wq * 32 + iq) * 512 + h * 64 + l32;
      out[orow]      = O1[0][r] * i1 - 0.5f * O2[0][r] * i2;
      out[orow + 32] = O1[1][r] * i1 - 0.5f * O2[1][r] * i2;
    }
  }
}

// ---------------------------------------------------------------- launcher
extern "C" void kernel_launch(void* const* d_in, const int* in_sizes, int n_in,
                              void* d_out, int out_size, void* d_ws, size_t ws_size,
                              hipStream_t stream) {
  (void)in_sizes; (void)n_in; (void)out_size; (void)ws_size;
  const float* x  = (const float*)d_in[0];
  const float* Wq = (const float*)d_in[1];
  const float* bq = (const float*)d_in[2];
  const float* Wk = (const float*)d_in[3];
  const float* bk = (const float*)d_in[4];
  const float* Wv = (const float*)d_in[5];
  const float* bv = (const float*)d_in[6];
  float* out = (float*)d_out;

  char* ws = (char*)d_ws;
  u16* xb = (u16*)(ws);                    // 4096*512*2   = 4 MiB
  u16* wt = (u16*)(ws + 4194304);          // 2560*512*2   = 2.5 MiB
  u16* qa = (u16*)(ws + 6815744);          // 4*8*1024*128*2 = 8 MiB
  u16* ka = (u16*)(ws + 15204352);         // 8 MiB
  u16* va = (u16*)(ws + 23592960);         // 4*8*64*1024*2 = 4 MiB

  prep_kernel<<<dim3(168, 8), 256, 0, stream>>>(x, xb, Wq, Wk, Wv, wt);
  gemm_qkv<<<dim3(32, 20), 256, 0, stream>>>(xb, wt, bq, bk, bv, qa, ka, va);
  attn_kernel<<<dim3(32, 16), 256, 0, stream>>>(qa, ka, va, out);
}

// Round 13
// 128.270 us; speedup vs baseline: 1.4069x; 1.0359x over previous
//
#include <hip/hip_runtime.h>
#include <hip/hip_bf16.h>

typedef unsigned short u16;
typedef unsigned int u32;
typedef short s16x8 __attribute__((ext_vector_type(8)));
typedef short s16x4 __attribute__((ext_vector_type(4)));
typedef float f32x4 __attribute__((ext_vector_type(4)));
typedef float f32x16 __attribute__((ext_vector_type(16)));

// fp32 -> bf16 round-to-nearest-even
__device__ inline u16 f2bf(float f) {
  union { float f; unsigned int u; } v; v.f = f;
  unsigned int r = v.u + 0x7fffu + ((v.u >> 16) & 1u);
  return (u16)(r >> 16);
}

// pack two f32 -> bf16x2 in one instruction (no builtin on gfx950)
__device__ __forceinline__ u32 cvt_pk_bf16(float lo, float hi) {
  u32 r;
  asm("v_cvt_pk_bf16_f32 %0, %1, %2" : "=v"(r) : "v"(lo), "v"(hi));
  return r;
}

// async 16B global -> LDS DMA (lane i of the wave lands at ldsbase + i*16)
__device__ __forceinline__ void g2lds16(const u16* g, u16* l) {
  __builtin_amdgcn_global_load_lds((const __attribute__((address_space(1))) void*)g,
                                   (__attribute__((address_space(3))) void*)l, 16, 0, 0);
}

// ---------------------------------------------------------------- fused pre-pass:
// blocks x<40: W transpose+cast (64x64 tiles); x>=40: x cast (id = (x-40)*8+y)
__global__ __launch_bounds__(256) void prep_kernel(const float* __restrict__ x, u16* __restrict__ xb,
                                                   const float* __restrict__ Wq,
                                                   const float* __restrict__ Wk,
                                                   const float* __restrict__ Wv,
                                                   u16* __restrict__ wt) {
  if (blockIdx.x >= 40) {
    int i = (((blockIdx.x - 40) * 8 + blockIdx.y) * 256 + threadIdx.x) * 8;
    float4 a = *(const float4*)(x + i);
    float4 b = *(const float4*)(x + i + 4);
    s16x8 o;
    o[0] = (short)f2bf(a.x); o[1] = (short)f2bf(a.y);
    o[2] = (short)f2bf(a.z); o[3] = (short)f2bf(a.w);
    o[4] = (short)f2bf(b.x); o[5] = (short)f2bf(b.y);
    o[6] = (short)f2bf(b.z); o[7] = (short)f2bf(b.w);
    *(s16x8*)(xb + i) = o;
    return;
  }
  __shared__ float tile[64][65];
  int jg = blockIdx.x * 64;
  const float* src; int C, j0;
  if (jg < 1024)      { src = Wq; C = 1024; j0 = jg; }
  else if (jg < 2048) { src = Wk; C = 1024; j0 = jg - 1024; }
  else                { src = Wv; C = 512;  j0 = jg - 2048; }
  int k0 = blockIdx.y * 64;
  int tx = threadIdx.x % 64, ty4 = threadIdx.x / 64;
#pragma unroll
  for (int p = 0; p < 16; ++p) {
    int r = p * 4 + ty4;
    tile[r][tx] = src[(size_t)(k0 + r) * C + j0 + tx];
  }
  __syncthreads();
#pragma unroll
  for (int p = 0; p < 16; ++p) {
    int r = p * 4 + ty4;
    wt[(size_t)(jg + r) * 512 + k0 + tx] = f2bf(tile[tx][r]);
  }
}

// ---------------------------------------------------------------- fused QKV projection GEMM
// (m97 recipe). V-blocks (j0>=2048): operand-swapped MFMAs -> C^T -> coalesced va stores
// (verified R10). Q outputs PRE-SCALED by 0.18033688 (=1/sqrt(64)*log2(e)) so attn's
// exp2 input needs no per-element multiply.
__global__ __launch_bounds__(256, 2) void gemm_qkv(const u16* __restrict__ xb, const u16* __restrict__ wt,
                                                   const float* __restrict__ bq, const float* __restrict__ bk,
                                                   const float* __restrict__ bv,
                                                   u16* __restrict__ qa, u16* __restrict__ ka,
                                                   u16* __restrict__ va) {
  __shared__ __align__(16) u16 As[128 * 64];
  __shared__ __align__(16) u16 Bs[128 * 64];
  int m0 = blockIdx.x * 128, j0 = blockIdx.y * 128;
  bool isV = (j0 >= 2048);
  int tid = threadIdx.x;
  int w = tid >> 6, lane = tid & 63, quad = lane >> 4, l16 = lane & 15;
  int wr = (w >> 1) * 64, wc = (w & 1) * 64;

  int srow[4], scol[4], sbase[4];
#pragma unroll
  for (int it = 0; it < 4; ++it) {
    int s = it * 256 + tid;
    srow[it] = s >> 3;
    scol[it] = (s & 7) ^ ((s >> 3) & 7);
    sbase[it] = (s & ~63) * 8;
  }

  f32x4 acc[4][4];
#pragma unroll
  for (int i = 0; i < 4; ++i)
#pragma unroll
    for (int j = 0; j < 4; ++j)
#pragma unroll
      for (int r = 0; r < 4; ++r) acc[i][j][r] = 0.f;

  for (int kk = 0; kk < 8; ++kk) {
    int k0 = kk * 64;
    __syncthreads();
#pragma unroll
    for (int it = 0; it < 4; ++it) {
      g2lds16(xb + (size_t)(m0 + srow[it]) * 512 + k0 + scol[it] * 8, &As[sbase[it]]);
      g2lds16(wt + (size_t)(j0 + srow[it]) * 512 + k0 + scol[it] * 8, &Bs[sbase[it]]);
    }
    __syncthreads();
#pragma unroll
    for (int kb = 0; kb < 2; ++kb) {
      s16x8 af[4], bfr[4];
#pragma unroll
      for (int rb = 0; rb < 4; ++rb) {
        int row = wr + rb * 16 + l16;
        af[rb] = *(const s16x8*)(&As[row * 64 + (((kb * 4 + quad) ^ (row & 7)) * 8)]);
      }
#pragma unroll
      for (int cb = 0; cb < 4; ++cb) {
        int row = wc + cb * 16 + l16;
        bfr[cb] = *(const s16x8*)(&Bs[row * 64 + (((kb * 4 + quad) ^ (row & 7)) * 8)]);
      }
      if (isV) {
#pragma unroll
        for (int rb = 0; rb < 4; ++rb)
#pragma unroll
          for (int cb = 0; cb < 4; ++cb)
            acc[rb][cb] = __builtin_amdgcn_mfma_f32_16x16x32_bf16(bfr[cb], af[rb], acc[rb][cb], 0, 0, 0);
      } else {
#pragma unroll
        for (int rb = 0; rb < 4; ++rb)
#pragma unroll
          for (int cb = 0; cb < 4; ++cb)
            acc[rb][cb] = __builtin_amdgcn_mfma_f32_16x16x32_bf16(af[rb], bfr[cb], acc[rb][cb], 0, 0, 0);
      }
    }
  }

  if (isV) {
    // transposed acc: row(quad*4+r) -> j, col(l16) -> m. Lanes -> consecutive n.
#pragma unroll
    for (int cb = 0; cb < 4; ++cb) {
#pragma unroll
      for (int rb = 0; rb < 4; ++rb) {
        int m = m0 + wr + rb * 16 + l16;
        int bidx = m >> 10, n = m & 1023;
#pragma unroll
        for (int r = 0; r < 4; ++r) {
          int jj = j0 - 2048 + wc + cb * 16 + quad * 4 + r;
          int h = jj >> 6, d = jj & 63;
          float bias = bv[jj];
          va[((size_t)((bidx * 8 + h) * 64 + d)) * 1024 + n] = f2bf(acc[rb][cb][r] + bias);
        }
      }
    }
  } else {
#pragma unroll
    for (int cb = 0; cb < 4; ++cb) {
      int j = j0 + wc + cb * 16 + l16;
      bool isQ = (j < 1024);
      float bias = isQ ? bq[j] : bk[j - 1024];
#pragma unroll
      for (int rb = 0; rb < 4; ++rb) {
#pragma unroll
        for (int r = 0; r < 4; ++r) {
          int m = m0 + wr + rb * 16 + quad * 4 + r;
          int bidx = m >> 10, n = m & 1023;
          float val = acc[rb][cb][r] + bias;
          u16 o = f2bf(isQ ? val * 0.18033688f : val);   // pre-scale Q for attn's exp2
          if (isQ) {
            int h = j >> 7, r2 = j & 127;
            qa[((size_t)((bidx * 8 + h) * 1024 + n)) * 128 + r2] = o;
          } else {
            int jj = j - 1024, h = jj >> 7, r2 = jj & 127;
            ka[((size_t)((bidx * 8 + h) * 1024 + n)) * 128 + r2] = o;
          }
        }
      }
    }
  }
}

// ---------------------------------------------------------------- differential attention v11
// v8's verified math with KVBLK 64->32 and BOTH K and V double-buffered:
//  - 48KB LDS/block -> 3 blocks/CU (was 2): 12 waves/CU, 3 independent barrier groups;
//  - ONE __syncthreads per tile (barrier A gone), full tile body covers the DMA;
//  - 16 tiles of 32n per team; same swapped-QK / k(n)-permuted register-P / VALU
//    denominator; K swizzle identical (row&15 fold), V swizzle rederived for
//    4-chunk rows: chunk ^ ((row>>1)&3), applied on both DMA-source and read side.
__global__ __launch_bounds__(256, 2) void attn_kernel(const u16* __restrict__ qa, const u16* __restrict__ ka,
                                                      const u16* __restrict__ va, float* __restrict__ out) {
  __shared__ __align__(16) u16 smem[24576];   // 49152 B: two 24KB team halves
  int bh = blockIdx.x, b = bh >> 3, h = bh & 7;
  int q0 = blockIdx.y * 64;
  int tid = threadIdx.x, w = tid >> 6, lane = tid & 63;
  int l32 = lane & 31, hi = lane >> 5;
  int team = w >> 1, wq = w & 1, t = tid & 127;
  u16* hb = smem + team * 12288;
  u16* const KbA = hb;            // 4096 u16 (32n x 128k)
  u16* const KbB = hb + 4096;
  u16* const VbA = hb + 8192;     // 2048 u16 (64d x 32n)
  u16* const VbB = hb + 10240;

  // Q fragments (pre-scaled): B-side of swapped QK. col=q=l32
  const u16* qrow = qa + (size_t)(bh * 1024 + q0 + wq * 32 + l32) * 128;
  s16x8 qf[2][4];
#pragma unroll
  for (int hh = 0; hh < 2; ++hh)
#pragma unroll
    for (int kb = 0; kb < 4; ++kb)
      qf[hh][kb] = *(const s16x8*)(qrow + 64 * hh + 16 * kb + 8 * hi);

  f32x16 O1[2], O2[2];
#pragma unroll
  for (int d = 0; d < 2; ++d)
#pragma unroll
    for (int r = 0; r < 16; ++r) { O1[d][r] = 0.f; O2[d][r] = 0.f; }
  float ds1 = 0.f, ds2 = 0.f;

  // staging precompute (per 128-thread team)
  int r0 = t >> 4, c0 = t & 15;                 // K: 4 slots -> rows it*8 + r0, chunk c0^(row&15)
  int rv = t >> 2, cv = (t & 3) ^ ((t >> 3) & 3);  // V: rows it*32 + rv, chunk cv (constant/thread)
  const u16* kgbase = ka + (size_t)bh * 1024 * 128;
  const u16* vgbase = va + (size_t)bh * 64 * 1024;
  int nbase = team * 512;                       // this team's n range: 16 tiles of 32

  auto stageK = [&](int n0, u16* Kd) {
#pragma unroll
    for (int it = 0; it < 4; ++it) {
      int row = it * 8 + r0;                    // 0..31
      g2lds16(kgbase + (size_t)(n0 + row) * 128 + (c0 ^ (row & 15)) * 8,
              Kd + (it * 128 + (t & 64)) * 8);
    }
  };
  auto stageV = [&](int n0, u16* Vd) {
#pragma unroll
    for (int it = 0; it < 2; ++it) {
      int row = it * 32 + rv;                   // d: 0..63
      g2lds16(vgbase + (size_t)row * 1024 + n0 + cv * 8,
              Vd + (it * 128 + (t & 64)) * 8);
    }
  };

  stageK(nbase, KbA);
  stageV(nbase, VbA);
  __syncthreads();   // drain DMA for tile 0

  for (int kt = 0; kt < 16; ++kt) {
    int cur = kt & 1;
    u16* const KsC = cur ? KbB : KbA;
    u16* const VsC = cur ? VbB : VbA;
    if (kt < 15) {   // prefetch tile kt+1 into the other buffers; in flight until end barrier
      int n1 = nbase + (kt + 1) * 32;
      stageK(n1, cur ? KbA : KbB);
      stageV(n1, cur ? VbA : VbB);
    }

    // QK^T (swapped) + exp2 + in-register pack, per half.
    // C col=q=l32; row r -> n=(r&3)+8*(r>>2)+4*hi (r=8s+j -> n=16s+8(j>>2)+4hi+(j&3))
    s16x8 pa[2][2];   // [hh][s]: A-frag for PV step s (n-block 16s..16s+15)
#pragma unroll
    for (int hh = 0; hh < 2; ++hh) {
      f32x16 sv;
#pragma unroll
      for (int r = 0; r < 16; ++r) sv[r] = 0.f;
      int rbase = l32 * 128, rx15 = l32 & 15;
#pragma unroll
      for (int kb = 0; kb < 4; ++kb) {
        s16x8 kf = *(const s16x8*)(&KsC[rbase + (((8 * hh + 2 * kb + hi) ^ rx15) * 8)]);
        sv = __builtin_amdgcn_mfma_f32_32x32x16_bf16(kf, qf[hh][kb], sv, 0, 0, 0);
      }
      float dsl = 0.f;
#pragma unroll
      for (int s = 0; s < 2; ++s) {
        float e[8];
#pragma unroll
        for (int j = 0; j < 8; ++j) {
          e[j] = __builtin_exp2f(sv[s * 8 + j]);   // Q pre-scaled in gemm
          dsl += e[j];
        }
        union { u32 wd[4]; s16x8 v; } u;
        u.wd[0] = cvt_pk_bf16(e[0], e[1]);
        u.wd[1] = cvt_pk_bf16(e[2], e[3]);
        u.wd[2] = cvt_pk_bf16(e[4], e[5]);
        u.wd[3] = cvt_pk_bf16(e[6], e[7]);
        pa[hh][s] = u.v;
      }
      if (hh == 0) ds1 += dsl; else ds2 += dsl;
    }

    // V B-frags under the same k(n)-map: lane (d=l32+32dblk, hi) el j holds
    // V[n = 16s + 8*(j>>2) + 4hi + (j&3)][d] -> two 8B reads from swizzled V^T [64][32]
    s16x8 vB[2][2];   // [s][dblk]
#pragma unroll
    for (int dblk = 0; dblk < 2; ++dblk) {
      int row = dblk * 32 + l32, rbase = row * 32, rx = (row >> 1) & 3;
#pragma unroll
      for (int s = 0; s < 2; ++s) {
        union { s16x4 hl[2]; s16x8 v; } u;
        u.hl[0] = *(const s16x4*)(&VsC[rbase + (((2 * s) ^ rx) * 8) + 4 * hi]);
        u.hl[1] = *(const s16x4*)(&VsC[rbase + (((2 * s + 1) ^ rx) * 8) + 4 * hi]);
        vB[s][dblk] = u.v;
      }
    }

    // PV: O[q][d] += P[q][n] V[n][d]; C row -> q, col = d
#pragma unroll
    for (int s = 0; s < 2; ++s)
#pragma unroll
      for (int dblk = 0; dblk < 2; ++dblk) {
        O1[dblk] = __builtin_amdgcn_mfma_f32_32x32x16_bf16(pa[0][s], vB[s][dblk], O1[dblk], 0, 0, 0);
        O2[dblk] = __builtin_amdgcn_mfma_f32_32x32x16_bf16(pa[1][s], vB[s][dblk], O2[dblk], 0, 0, 0);
      }

    __syncthreads();   // single barrier per tile: drains K+V prefetch DMA, syncs buffers
  }

  // ---- epilogue: merge team partials via LDS scratch, normalize, combine, store
  float* scr = (float*)smem;   // 33.8KB over freed buffers (48KB available)
  int mbase = wq * 4224 + lane;
  if (team == 1) {
#pragma unroll
    for (int r = 0; r < 16; ++r) {
      scr[mbase + r * 64]        = O1[0][r];
      scr[mbase + (16 + r) * 64] = O1[1][r];
      scr[mbase + (32 + r) * 64] = O2[0][r];
      scr[mbase + (48 + r) * 64] = O2[1][r];
    }
    scr[mbase + 64 * 64] = ds1;
    scr[mbase + 65 * 64] = ds2;
  }
  __syncthreads();
  if (team == 0) {
#pragma unroll
    for (int r = 0; r < 16; ++r) {
      O1[0][r] += scr[mbase + r * 64];
      O1[1][r] += scr[mbase + (16 + r) * 64];
      O2[0][r] += scr[mbase + (32 + r) * 64];
      O2[1][r] += scr[mbase + (48 + r) * 64];
    }
    ds1 += scr[mbase + 64 * 64];
    ds2 += scr[mbase + 65 * 64];
    ds1 += __shfl_xor(ds1, 32, 64);   // combine the two hi-halves' n-subsets
    ds2 += __shfl_xor(ds2, 32, 64);
    float inv1 = 1.0f / ds1, inv2 = 1.0f / ds2;   // lane l holds inv for q = l32
#pragma unroll
    for (int r = 0; r < 16; ++r) {
      int iq = (r & 3) + 8 * (r >> 2) + 4 * hi;   // this reg's q within the wave's 32
      float i1 = __shfl(inv1, iq, 64);
      float i2 = __shfl(inv2, iq, 64);
      size_t orow = (size_t)(b * 1024 + q0 + wq * 32 + iq) * 512 + h * 64 + l32;
      out[orow]      = O1[0][r] * i1 - 0.5f * O2[0][r] * i2;
      out[orow + 32] = O1[1][r] * i1 - 0.5f * O2[1][r] * i2;
    }
  }
}

// ---------------------------------------------------------------- launcher
extern "C" void kernel_launch(void* const* d_in, const int* in_sizes, int n_in,
                              void* d_out, int out_size, void* d_ws, size_t ws_size,
                              hipStream_t stream) {
  (void)in_sizes; (void)n_in; (void)out_size; (void)ws_size;
  const float* x  = (const float*)d_in[0];
  const float* Wq = (const float*)d_in[1];
  const float* bq = (const float*)d_in[2];
  const float* Wk = (const float*)d_in[3];
  const float* bk = (const float*)d_in[4];
  const float* Wv = (const float*)d_in[5];
  const float* bv = (const float*)d_in[6];
  float* out = (float*)d_out;

  char* ws = (char*)d_ws;
  u16* xb = (u16*)(ws);                    // 4096*512*2   = 4 MiB
  u16* wt = (u16*)(ws + 4194304);          // 2560*512*2   = 2.5 MiB
  u16* qa = (u16*)(ws + 6815744);          // 4*8*1024*128*2 = 8 MiB
  u16* ka = (u16*)(ws + 15204352);         // 8 MiB
  u16* va = (u16*)(ws + 23592960);         // 4*8*64*1024*2 = 4 MiB

  prep_kernel<<<dim3(168, 8), 256, 0, stream>>>(x, xb, Wq, Wk, Wv, wt);
  gemm_qkv<<<dim3(32, 20), 256, 0, stream>>>(xb, wt, bq, bk, bv, qa, ka, va);
  attn_kernel<<<dim3(32, 16), 256, 0, stream>>>(qa, ka, va, out);
}